// Round 1
// baseline (185.108 us; speedup 1.0000x reference)
//
#include <hip/hip_runtime.h>

// Bilinear warp: out[b,c,i,j] = bilerp(trace[b,c], i + off0*256, j + off1*256)
// B=64, C=3, H=W=256. All fp32.

constexpr int Hc = 256;
constexpr int Wc = 256;
constexpr int Cc = 3;
constexpr int Bc = 64;
constexpr int HWc = Hc * Wc;   // 65536

__global__ __launch_bounds__(256) void warp_bilinear_kernel(
    const float* __restrict__ trace,
    const float* __restrict__ offsets,
    float* __restrict__ out)
{
    const int idx = blockIdx.x * blockDim.x + threadIdx.x;  // [0, B*HW)
    const int b = idx >> 16;        // / HW (HW = 65536)
    const int p = idx & (HWc - 1);  // % HW
    const int i = p >> 8;           // row
    const int j = p & (Wc - 1);     // col

    // Coalesced offset loads (channel 0 = x/row offset, channel 1 = y/col offset)
    const float* offb = offsets + (size_t)b * 2 * HWc;
    const float ox = offb[p] * 256.0f;
    const float oy = offb[HWc + p] * 256.0f;

    // Sample position, clamped like the reference (clip to [0, 255])
    const float sx = fminf(fmaxf((float)i + ox, 0.0f), 255.0f);
    const float sy = fminf(fmaxf((float)j + oy, 0.0f), 255.0f);

    const float flx = floorf(sx);
    const float fly = floorf(sy);
    const int x0 = (int)flx;
    const int y0 = (int)fly;
    const int x1 = (int)ceilf(sx);
    const int y1 = (int)ceilf(sy);
    const float fx = sx - flx;
    const float fy = sy - fly;

    const int r0 = x0 << 8;  // row offsets into a 256x256 plane
    const int r1 = x1 << 8;

    const float* tb = trace + (size_t)b * Cc * HWc;
    float* ob = out + (size_t)b * Cc * HWc;

    // Reference math order: x_u = v00 + (v10 - v00)*fx ; x_b = v01 + (v11 - v01)*fx ;
    // out = x_u + (x_b - x_u)*fy
    #pragma unroll
    for (int c = 0; c < Cc; ++c) {
        const float* tc = tb + c * HWc;
        const float v00 = tc[r0 + y0];
        const float v01 = tc[r0 + y1];
        const float v10 = tc[r1 + y0];
        const float v11 = tc[r1 + y1];
        const float xu = v00 + (v10 - v00) * fx;
        const float xb = v01 + (v11 - v01) * fx;
        ob[c * HWc + p] = xu + (xb - xu) * fy;
    }
}

extern "C" void kernel_launch(void* const* d_in, const int* in_sizes, int n_in,
                              void* d_out, int out_size, void* d_ws, size_t ws_size,
                              hipStream_t stream) {
    const float* trace = (const float*)d_in[0];
    const float* offsets = (const float*)d_in[1];
    float* out = (float*)d_out;

    const int total = Bc * HWc;                 // 4,194,304 threads (1 per pixel)
    const int block = 256;
    const int grid = total / block;             // 16384 blocks, exact
    warp_bilinear_kernel<<<grid, block, 0, stream>>>(trace, offsets, out);
}

// Round 2
// 158.168 us; speedup vs baseline: 1.1703x; 1.1703x over previous
//
#include <hip/hip_runtime.h>

// Bilinear warp: out[b,c,i,j] = bilerp(trace[b,c], i + off0*256, j + off1*256)
// B=64, C=3, H=W=256. All fp32.
//
// Strategy: (1) repack trace NCHW -> NHWC4 (16B/pixel) into d_ws so each
// bilinear corner is ONE global_load_dwordx4 (4 gathers/pixel instead of 12);
// (2) XCD-chunked block swizzle so each XCD's live gather working set is ~1
// batch image (1 MB) -> L2-resident.

constexpr int Hc = 256;
constexpr int Wc = 256;
constexpr int Cc = 3;
constexpr int Bc = 64;
constexpr int HWc = Hc * Wc;                       // 65536
constexpr size_t NHWC4_BYTES = (size_t)Bc * HWc * 4 * sizeof(float);  // 67,108,864

// ---------- Kernel 1: NCHW -> NHWC4 repack (streaming, memory-bound) ----------
__global__ __launch_bounds__(256) void repack_nhwc4_kernel(
    const float* __restrict__ trace, float4* __restrict__ nhwc)
{
    const int idx = blockIdx.x * blockDim.x + threadIdx.x;  // [0, B*HW)
    const int b = idx >> 16;
    const int p = idx & (HWc - 1);
    const float* tb = trace + (size_t)b * Cc * HWc;
    float4 v;
    v.x = tb[p];
    v.y = tb[HWc + p];
    v.z = tb[2 * HWc + p];
    v.w = 0.0f;
    nhwc[(size_t)b * HWc + p] = v;
}

// ---------- Kernel 2: gather + bilerp from NHWC4 ----------
__global__ __launch_bounds__(256) void warp_gather_nhwc4_kernel(
    const float4* __restrict__ nhwc,
    const float* __restrict__ offsets,
    float* __restrict__ out)
{
    // XCD-chunked swizzle: 16384 blocks, 8 XCDs -> XCD k owns contiguous
    // block range [k*2048, (k+1)*2048).
    const int bid = blockIdx.x;
    const int sb = ((bid & 7) << 11) | (bid >> 3);
    const int idx = (sb << 8) | threadIdx.x;

    const int b = idx >> 16;
    const int p = idx & (HWc - 1);
    const int i = p >> 8;
    const int j = p & (Wc - 1);

    const float* offb = offsets + (size_t)b * 2 * HWc;
    const float ox = offb[p] * 256.0f;
    const float oy = offb[HWc + p] * 256.0f;

    const float sx = fminf(fmaxf((float)i + ox, 0.0f), 255.0f);
    const float sy = fminf(fmaxf((float)j + oy, 0.0f), 255.0f);

    const float flx = floorf(sx);
    const float fly = floorf(sy);
    const int x0 = (int)flx;
    const int y0 = (int)fly;
    const int x1 = (int)ceilf(sx);
    const int y1 = (int)ceilf(sy);
    const float fx = sx - flx;
    const float fy = sy - fly;

    const int r0 = x0 << 8;
    const int r1 = x1 << 8;

    const float4* tb = nhwc + (size_t)b * HWc;
    const float4 v00 = tb[r0 + y0];
    const float4 v01 = tb[r0 + y1];
    const float4 v10 = tb[r1 + y0];
    const float4 v11 = tb[r1 + y1];

    float* ob = out + (size_t)b * Cc * HWc;
    // Reference math order per channel:
    {
        const float xu = v00.x + (v10.x - v00.x) * fx;
        const float xb = v01.x + (v11.x - v01.x) * fx;
        ob[p] = xu + (xb - xu) * fy;
    }
    {
        const float xu = v00.y + (v10.y - v00.y) * fx;
        const float xb = v01.y + (v11.y - v01.y) * fx;
        ob[HWc + p] = xu + (xb - xu) * fy;
    }
    {
        const float xu = v00.z + (v10.z - v00.z) * fx;
        const float xb = v01.z + (v11.z - v01.z) * fx;
        ob[2 * HWc + p] = xu + (xb - xu) * fy;
    }
}

// ---------- Fallback (if workspace too small): original fused kernel ----------
__global__ __launch_bounds__(256) void warp_bilinear_kernel(
    const float* __restrict__ trace,
    const float* __restrict__ offsets,
    float* __restrict__ out)
{
    const int idx = blockIdx.x * blockDim.x + threadIdx.x;
    const int b = idx >> 16;
    const int p = idx & (HWc - 1);
    const int i = p >> 8;
    const int j = p & (Wc - 1);

    const float* offb = offsets + (size_t)b * 2 * HWc;
    const float ox = offb[p] * 256.0f;
    const float oy = offb[HWc + p] * 256.0f;

    const float sx = fminf(fmaxf((float)i + ox, 0.0f), 255.0f);
    const float sy = fminf(fmaxf((float)j + oy, 0.0f), 255.0f);

    const float flx = floorf(sx);
    const float fly = floorf(sy);
    const int x0 = (int)flx;
    const int y0 = (int)fly;
    const int x1 = (int)ceilf(sx);
    const int y1 = (int)ceilf(sy);
    const float fx = sx - flx;
    const float fy = sy - fly;

    const int r0 = x0 << 8;
    const int r1 = x1 << 8;

    const float* tb = trace + (size_t)b * Cc * HWc;
    float* ob = out + (size_t)b * Cc * HWc;

    #pragma unroll
    for (int c = 0; c < Cc; ++c) {
        const float* tc = tb + c * HWc;
        const float v00 = tc[r0 + y0];
        const float v01 = tc[r0 + y1];
        const float v10 = tc[r1 + y0];
        const float v11 = tc[r1 + y1];
        const float xu = v00 + (v10 - v00) * fx;
        const float xb = v01 + (v11 - v01) * fx;
        ob[c * HWc + p] = xu + (xb - xu) * fy;
    }
}

extern "C" void kernel_launch(void* const* d_in, const int* in_sizes, int n_in,
                              void* d_out, int out_size, void* d_ws, size_t ws_size,
                              hipStream_t stream) {
    const float* trace = (const float*)d_in[0];
    const float* offsets = (const float*)d_in[1];
    float* out = (float*)d_out;

    const int total = Bc * HWc;      // 4,194,304
    const int block = 256;
    const int grid = total / block;  // 16384

    if (ws_size >= NHWC4_BYTES) {
        float4* nhwc = (float4*)d_ws;
        repack_nhwc4_kernel<<<grid, block, 0, stream>>>(trace, nhwc);
        warp_gather_nhwc4_kernel<<<grid, block, 0, stream>>>(nhwc, offsets, out);
    } else {
        warp_bilinear_kernel<<<grid, block, 0, stream>>>(trace, offsets, out);
    }
}